// Round 12
// baseline (79.596 us; speedup 1.0000x reference)
//
#include <hip/hip_runtime.h>
#include <math.h>

#define GG   64
#define NBG  512           // B*G
#define TOT  2097152       // B*N
#define PTS  1024          // points per block (256 thr x 4)
#define NBLK (TOT / PTS)   // 2048

// ws float layout:
//   [0    ..  512) zsumP
//   [512  .. 1024) zsumT
//   [1024 .. 1536) cnt
//   [1536 .. 1536+6*2048) per-block partials, transposed
#define ZP_F   0
#define ZT_F   512
#define CNT_F  1024
#define PART_F 1536
#define WS_ZERO_BYTES (1536 * 4)

#define LN2   0.6931471805599453f
#define LOG2E 1.4426950408889634f

typedef float vf4 __attribute__((ext_vector_type(4)));
typedef int   vi4 __attribute__((ext_vector_type(4)));

__device__ __forceinline__ float fexp2(float x) { return __builtin_amdgcn_exp2f(x); }
__device__ __forceinline__ float flog2(float x) { return __builtin_amdgcn_logf(x); }
__device__ __forceinline__ float flog1p(float x) { return flog2(1.0f + x) * LN2; }

// non-temporal vector loads (last-touch streams only)
__device__ __forceinline__ float4 ntl4(const float4* p) {
    vf4 v = __builtin_nontemporal_load((const vf4*)p);
    return make_float4(v.x, v.y, v.z, v.w);
}
__device__ __forceinline__ int4 ntl4i(const int4* p) {
    vi4 v = __builtin_nontemporal_load((const vi4*)p);
    return make_int4(v.x, v.y, v.z, v.w);
}

__device__ __forceinline__ float wredf(float v) {
#pragma unroll
    for (int o = 32; o > 0; o >>= 1) v += __shfl_down(v, o, 64);
    return v;
}

// ---- Kernel 1: per-(b,g) z sums + counts. REGULAR loads (warm cache for k_loss).
__global__ __launch_bounds__(256) void k_group(const float* __restrict__ pp,
                                               const float* __restrict__ tp,
                                               const int* __restrict__ mask,
                                               const int* __restrict__ grp,
                                               float* __restrict__ ws) {
    __shared__ float4 bufA[768], bufB[768];
    __shared__ float sP[GG], sT[GG], sC[GG];
    const int tid = threadIdx.x;
    if (tid < GG) { sP[tid] = 0.f; sT[tid] = 0.f; sC[tid] = 0.f; }

    const int base = blockIdx.x * PTS;
    const int b = base >> 18;
    const int p0 = base + 4 * tid;

    const float4* gx = (const float4*)(pp + (size_t)base * 3);
    const float4* gy = (const float4*)(tp + (size_t)base * 3);
#pragma unroll
    for (int j = 0; j < 3; j++) {
        bufA[tid + 256 * j] = gx[tid + 256 * j];
        bufB[tid + 256 * j] = gy[tid + 256 * j];
    }
    const int4 M  = *(const int4*)(mask + p0);
    const int4 Gp = *(const int4*)(grp + p0);
    __syncthreads();

    float4 a0 = bufA[3 * tid], a1 = bufA[3 * tid + 1], a2 = bufA[3 * tid + 2];
    float4 b0 = bufB[3 * tid], b1 = bufB[3 * tid + 1], b2 = bufB[3 * tid + 2];
    // z components: pt0=a0.z pt1=a1.y pt2=a2.x pt3=a2.w
    if (M.x) { atomicAdd(&sP[Gp.x], a0.z); atomicAdd(&sT[Gp.x], b0.z); atomicAdd(&sC[Gp.x], 1.f); }
    if (M.y) { atomicAdd(&sP[Gp.y], a1.y); atomicAdd(&sT[Gp.y], b1.y); atomicAdd(&sC[Gp.y], 1.f); }
    if (M.z) { atomicAdd(&sP[Gp.z], a2.x); atomicAdd(&sT[Gp.z], b2.x); atomicAdd(&sC[Gp.z], 1.f); }
    if (M.w) { atomicAdd(&sP[Gp.w], a2.w); atomicAdd(&sT[Gp.w], b2.w); atomicAdd(&sC[Gp.w], 1.f); }
    __syncthreads();

    if (tid < GG) {
        float c = sC[tid];
        if (c != 0.0f) {
            int e = b * GG + tid;
            atomicAdd(&ws[ZP_F + e], sP[tid]);
            atomicAdd(&ws[ZT_F + e], sT[tid]);
            atomicAdd(&ws[CNT_F + e], c);
        }
    }
}

// ---- Kernel 2: main loss. Pairs computed in-block from global sum tables.
__global__ __launch_bounds__(256) void k_loss(const float* __restrict__ pp,
                                              const float* __restrict__ tp,
                                              const float* __restrict__ p2,
                                              const float* __restrict__ t2,
                                              const float* __restrict__ pv,
                                              const float* __restrict__ tv,
                                              const float* __restrict__ pd,
                                              const float* __restrict__ td,
                                              const float* __restrict__ pn,
                                              const float* __restrict__ tn,
                                              const float* __restrict__ cf,
                                              const int* __restrict__ mask,
                                              const int* __restrict__ grp,
                                              float* __restrict__ ws) {
    __shared__ float4 bufA[768], bufB[768];
    __shared__ float sPairs[2 * GG];
    const int tid = threadIdx.x;
    const int base = blockIdx.x * PTS;
    const int p0 = base + 4 * tid;
    const int b = base >> 18;

    // ---- preamble: this batch's 64 inverse-safe-mean pairs (replaces k_groups_final)
    if (tid < GG) {
        int e = b * GG + tid;
        float c = ws[CNT_F + e];
        float mP = (c > 0.f) ? ws[ZP_F + e] / fmaxf(c, 1.f) : 1.f;
        float mT = (c > 0.f) ? ws[ZT_F + e] / fmaxf(c, 1.f) : 1.f;
        sPairs[2 * tid]     = 1.f / fmaxf(fabsf(mP), 1e-6f);
        sPairs[2 * tid + 1] = 1.f / fmaxf(fabsf(mT), 1e-6f);
    }

    const int4 M  = ntl4i((const int4*)(mask + p0));
    const int4 Gp = ntl4i((const int4*)(grp + p0));
    const float w[4] = {(float)M.x, (float)M.y, (float)M.z, (float)M.w};
    const int Gs[4] = {Gp.x, Gp.y, Gp.z, Gp.w};
    __syncthreads();

    float iP[4], iT[4];
#pragma unroll
    for (int k = 0; k < 4; k++) {
        iP[k] = sPairs[2 * Gs[k]];
        iT[k] = sPairs[2 * Gs[k] + 1];
    }

    float s3d = 0.f, s2 = 0.f, sv = 0.f, sd = 0.f, sn = 0.f, sc = 0.f;

    {   // L_2D
        float4 Aa = ntl4(((const float4*)(p2 + 2 * (size_t)p0)) + 0);
        float4 Ab = ntl4(((const float4*)(p2 + 2 * (size_t)p0)) + 1);
        float4 Ba = ntl4(((const float4*)(t2 + 2 * (size_t)p0)) + 0);
        float4 Bb = ntl4(((const float4*)(t2 + 2 * (size_t)p0)) + 1);
        s2 = w[0] * (fabsf(Aa.x - Ba.x) + fabsf(Aa.y - Ba.y))
           + w[1] * (fabsf(Aa.z - Ba.z) + fabsf(Aa.w - Ba.w))
           + w[2] * (fabsf(Ab.x - Bb.x) + fabsf(Ab.y - Bb.y))
           + w[3] * (fabsf(Ab.z - Bb.z) + fabsf(Ab.w - Bb.w));
    }
    {   // L_vis + L_conf
        float4 X  = ntl4((const float4*)(pv + p0));
        float4 Tg = ntl4((const float4*)(tv + p0));
        float4 C  = ntl4((const float4*)(cf + p0));
        const float xs[4] = {X.x, X.y, X.z, X.w};
        const float ts[4] = {Tg.x, Tg.y, Tg.z, Tg.w};
        const float cs[4] = {C.x, C.y, C.z, C.w};
#pragma unroll
        for (int k = 0; k < 4; k++) {
            float x = xs[k];
            float soft = flog2(1.0f + fexp2(-fabsf(x) * LOG2E)) * LN2;
            sv += w[k] * (fmaxf(x, 0.f) - x * ts[k] + soft);
            sc += w[k] * cs[k];
        }
    }

    // ---- Phase 1: pp/tp -> L_3D
    {
        const float4* gx = (const float4*)(pp + (size_t)base * 3);
        const float4* gy = (const float4*)(tp + (size_t)base * 3);
#pragma unroll
        for (int j = 0; j < 3; j++) {
            bufA[tid + 256 * j] = ntl4(&gx[tid + 256 * j]);
            bufB[tid + 256 * j] = ntl4(&gy[tid + 256 * j]);
        }
        __syncthreads();
        float P[12], T[12];
        *(float4*)&P[0] = bufA[3 * tid]; *(float4*)&P[4] = bufA[3 * tid + 1]; *(float4*)&P[8] = bufA[3 * tid + 2];
        *(float4*)&T[0] = bufB[3 * tid]; *(float4*)&T[4] = bufB[3 * tid + 1]; *(float4*)&T[8] = bufB[3 * tid + 2];
        __syncthreads();
#pragma unroll
        for (int k = 0; k < 4; k++) {
            float acc = 0.f;
#pragma unroll
            for (int c = 0; c < 3; c++) {
                float a = P[3 * k + c] * iP[k];
                float bb = T[3 * k + c] * iT[k];
                acc += fabsf(copysignf(flog1p(fabsf(a)), a) - copysignf(flog1p(fabsf(bb)), bb));
            }
            s3d += w[k] * acc;
        }
    }
    // ---- Phase 2: pd/td -> L_disp
    {
        const float4* gx = (const float4*)(pd + (size_t)base * 3);
        const float4* gy = (const float4*)(td + (size_t)base * 3);
#pragma unroll
        for (int j = 0; j < 3; j++) {
            bufA[tid + 256 * j] = ntl4(&gx[tid + 256 * j]);
            bufB[tid + 256 * j] = ntl4(&gy[tid + 256 * j]);
        }
        __syncthreads();
        float P[12], T[12];
        *(float4*)&P[0] = bufA[3 * tid]; *(float4*)&P[4] = bufA[3 * tid + 1]; *(float4*)&P[8] = bufA[3 * tid + 2];
        *(float4*)&T[0] = bufB[3 * tid]; *(float4*)&T[4] = bufB[3 * tid + 1]; *(float4*)&T[8] = bufB[3 * tid + 2];
        __syncthreads();
#pragma unroll
        for (int k = 0; k < 4; k++) {
            sd += w[k] * (fabsf(P[3 * k] - T[3 * k]) + fabsf(P[3 * k + 1] - T[3 * k + 1])
                        + fabsf(P[3 * k + 2] - T[3 * k + 2]));
        }
    }
    // ---- Phase 3: pn/tn -> L_normal
    {
        const float4* gx = (const float4*)(pn + (size_t)base * 3);
        const float4* gy = (const float4*)(tn + (size_t)base * 3);
#pragma unroll
        for (int j = 0; j < 3; j++) {
            bufA[tid + 256 * j] = ntl4(&gx[tid + 256 * j]);
            bufB[tid + 256 * j] = ntl4(&gy[tid + 256 * j]);
        }
        __syncthreads();
        float P[12], T[12];
        *(float4*)&P[0] = bufA[3 * tid]; *(float4*)&P[4] = bufA[3 * tid + 1]; *(float4*)&P[8] = bufA[3 * tid + 2];
        *(float4*)&T[0] = bufB[3 * tid]; *(float4*)&T[4] = bufB[3 * tid + 1]; *(float4*)&T[8] = bufB[3 * tid + 2];
#pragma unroll
        for (int k = 0; k < 4; k++) {
            float ax = P[3 * k], ay = P[3 * k + 1], az = P[3 * k + 2];
            float bx = T[3 * k], by = T[3 * k + 1], bz = T[3 * k + 2];
            float na = fmaf(ax, ax, fmaf(ay, ay, az * az));
            float nb = fmaf(bx, bx, fmaf(by, by, bz * bz));
            float dot = fmaf(ax, bx, fmaf(ay, by, az * bz));
            float r = __frsqrt_rn(fmaxf(na, 1e-24f)) * __frsqrt_rn(fmaxf(nb, 1e-24f));
            sn += w[k] * (1.0f - dot * r);
        }
    }

    // block reduction -> one non-atomic write per (block, term)
    __shared__ float sred[4][6];
    float vals[6] = {s3d, s2, sv, sd, sn, sc};
    int wid = threadIdx.x >> 6, lane = threadIdx.x & 63;
#pragma unroll
    for (int k = 0; k < 6; k++) {
        float r = wredf(vals[k]);
        if (lane == 0) sred[wid][k] = r;
    }
    __syncthreads();
    if (threadIdx.x < 6) {
        float tt = sred[0][threadIdx.x] + sred[1][threadIdx.x]
                 + sred[2][threadIdx.x] + sred[3][threadIdx.x];
        ws[PART_F + threadIdx.x * NBLK + blockIdx.x] = tt;
    }
}

// ---- Kernel 3: final reduce (2048 partials x 6 + nvalid) + combine. 1 block x 256
__global__ __launch_bounds__(256) void k_final(const float* __restrict__ ws,
                                               float* __restrict__ out) {
    const float* part = ws + PART_F;
    double loc[6] = {0, 0, 0, 0, 0, 0};
    for (int j = threadIdx.x; j < NBLK; j += 256) {
#pragma unroll
        for (int k = 0; k < 6; k++) loc[k] += (double)part[k * NBLK + j];
    }
    float nvloc = ws[CNT_F + threadIdx.x] + ws[CNT_F + threadIdx.x + 256];

    __shared__ double dred[4][6];
    __shared__ float nred[4];
    int wid = threadIdx.x >> 6, lane = threadIdx.x & 63;
#pragma unroll
    for (int k = 0; k < 6; k++) {
        double v = loc[k];
#pragma unroll
        for (int o = 32; o > 0; o >>= 1) v += __shfl_down(v, o, 64);
        if (lane == 0) dred[wid][k] = v;
    }
    {
        float v = wredf(nvloc);
        if (lane == 0) nred[wid] = v;
    }
    __syncthreads();
    if (threadIdx.x == 0) {
        double a[6];
#pragma unroll
        for (int k = 0; k < 6; k++)
            a[k] = dred[0][k] + dred[1][k] + dred[2][k] + dred[3][k];
        double nv = (double)(nred[0] + nred[1] + nred[2] + nred[3]);
        double d1 = nv + 1e-6;
        double d3 = 3.0 * nv + 1e-6;
        double l3d   = a[0] / d3;
        double l2d   = a[1] / (2.0 * nv + 1e-6);
        double lvis  = a[2] / d1;
        double ldisp = a[3] / d3;   // disp is (B,N,3): mask broadcasts to 3 channels
        double lnorm = a[4] / d1;
        double lconf = a[5] / d1;
        out[0] = (float)(l3d + 0.1 * (l2d + lvis + ldisp) + 0.5 * lnorm + 0.2 * lconf);
    }
}

extern "C" void kernel_launch(void* const* d_in, const int* in_sizes, int n_in,
                              void* d_out, int out_size, void* d_ws, size_t ws_size,
                              hipStream_t stream) {
    const float* pp = (const float*)d_in[0];
    const float* tp = (const float*)d_in[1];
    const float* p2 = (const float*)d_in[2];
    const float* t2 = (const float*)d_in[3];
    const float* pv = (const float*)d_in[4];
    const float* tv = (const float*)d_in[5];
    const float* pd = (const float*)d_in[6];
    const float* td = (const float*)d_in[7];
    const float* pn = (const float*)d_in[8];
    const float* tn = (const float*)d_in[9];
    const float* cf = (const float*)d_in[10];
    const int* mask = (const int*)d_in[11];
    const int* grp  = (const int*)d_in[12];
    float* ws = (float*)d_ws;
    float* out = (float*)d_out;

    (void)hipMemsetAsync(d_ws, 0, WS_ZERO_BYTES, stream);
    k_group<<<NBLK, 256, 0, stream>>>(pp, tp, mask, grp, ws);
    k_loss<<<NBLK, 256, 0, stream>>>(pp, tp, p2, t2, pv, tv, pd, td, pn, tn, cf, mask, grp, ws);
    k_final<<<1, 256, 0, stream>>>(ws, out);
}